// Round 5
// baseline (477.128 us; speedup 1.0000x reference)
//
#include <hip/hip_runtime.h>
#include <hip/hip_bf16.h>
#include <stdint.h>

#define D_MODEL 4096
#define D_BASE  8192
#define K_SUB   1024
#define N_TOK   8192

typedef __attribute__((ext_vector_type(8))) short bf16x8;
typedef __attribute__((ext_vector_type(4))) float f32x4;

__device__ __forceinline__ unsigned short f2bf(float f) {
    union { float f; uint32_t u; } c; c.f = f;
    uint32_t u = c.u;
    uint32_t r = u + 0x7FFFu + ((u >> 16) & 1u);   // round-to-nearest-even
    return (unsigned short)(r >> 16);
}

__device__ __forceinline__ void gload_lds16(const void* g, void* l) {
    __builtin_amdgcn_global_load_lds(
        (__attribute__((address_space(1))) void*)g,
        (__attribute__((address_space(3))) void*)l, 16, 0, 0);
}

#define VMCNT(N) do { __builtin_amdgcn_sched_barrier(0); \
    asm volatile("s_waitcnt vmcnt(" #N ")" ::: "memory"); } while (0)
#define PHASE_MID() do { __builtin_amdgcn_sched_barrier(0); __builtin_amdgcn_s_barrier(); \
    asm volatile("s_waitcnt lgkmcnt(0)" ::: "memory"); __builtin_amdgcn_sched_barrier(0); } while (0)
#define PHASE_END() do { __builtin_amdgcn_sched_barrier(0); __builtin_amdgcn_s_barrier(); } while (0)

// x (f32) -> xb (bf16), 8 elems/thread
__global__ void convert_x_kernel(const float* __restrict__ x, unsigned short* __restrict__ xb) {
    int t = blockIdx.x * 256 + threadIdx.x;
    const float4* p = (const float4*)x + (size_t)t * 2;
    float4 a = p[0], b = p[1];
    ushort4 lo, hi;
    lo.x = f2bf(a.x); lo.y = f2bf(a.y); lo.z = f2bf(a.z); lo.w = f2bf(a.w);
    hi.x = f2bf(b.x); hi.y = f2bf(b.y); hi.z = f2bf(b.z); hi.w = f2bf(b.w);
    *(ushort4*)(xb + (size_t)t * 8) = lo;
    *(ushort4*)(xb + (size_t)t * 8 + 4) = hi;
}

// Ut[n][k] = bf16(U[k][idx[n]]), via 64x64 LDS transpose tile.
__global__ __launch_bounds__(256) void gather_u_t(const float* __restrict__ U,
                                                  const int* __restrict__ idx,
                                                  unsigned short* __restrict__ Ut) {
    __shared__ unsigned short tile[64][66];
    __shared__ int lidx[64];
    const int t = threadIdx.x;
    const int n0 = (blockIdx.x & 15) * 64;
    const int k0 = (blockIdx.x >> 4) * 64;
    if (t < 64) lidx[t] = idx[n0 + t];
    __syncthreads();
    const int c = t & 63, r4 = t >> 6;
    #pragma unroll
    for (int p = 0; p < 16; ++p) {
        int kr = p * 4 + r4;
        tile[c][kr] = f2bf(U[(size_t)(k0 + kr) * D_BASE + lidx[c]]);
    }
    __syncthreads();
    #pragma unroll
    for (int p = 0; p < 16; ++p) {
        int nr = p * 4 + r4;
        Ut[(size_t)(n0 + nr) * D_MODEL + k0 + c] = tile[nr][c];
    }
}

// Vt[d][n] = bf16(V[idx[n]][d]), via 64x64 LDS transpose tile.
__global__ __launch_bounds__(256) void gather_v_t(const float* __restrict__ V,
                                                  const int* __restrict__ idx,
                                                  unsigned short* __restrict__ Vt) {
    __shared__ unsigned short tile[64][66];
    __shared__ int lidx[64];
    const int t = threadIdx.x;
    const int n0 = (blockIdx.x & 15) * 64;
    const int d0 = (blockIdx.x >> 4) * 64;
    if (t < 64) lidx[t] = idx[n0 + t];
    __syncthreads();
    const int c = t & 63, r4 = t >> 6;
    #pragma unroll
    for (int p = 0; p < 16; ++p) {
        int nr = p * 4 + r4;
        tile[nr][c] = f2bf(V[(size_t)lidx[nr] * D_MODEL + d0 + c]);
    }
    __syncthreads();
    #pragma unroll
    for (int p = 0; p < 16; ++p) {
        int dr = p * 4 + r4;
        Vt[(size_t)(d0 + dr) * K_SUB + n0 + c] = tile[c][dr];
    }
}

// ---------------- Unified GEMM: C[M][N] = A[M][K] @ Bt[N][K]^T ----------------
// BM=256 BN=128 BK=64, 8 waves 4M x 2N -> wave tile 64x64.
// A: global_load_lds staged (linear LDS + XOR-swizzle via pre-swizzled source),
//    double-buffered, 64 KB. Staged as 2 halves (128 rows, 2 loads/thread each).
// B: NO LDS — per-lane global->VGPR fragment loads (16B, 64B-line aligned per
//    16-lane group). B-tile/K-step = 16 KB -> L1-resident; 4x wave amp absorbed
//    by L1, not LDS. Removes B ds_write + ds_read from the LDS pipe (the
//    measured bottleneck: reads+writes 2490 cyc vs 1030 MFMA cyc per K-tile).
// Phases: 2 per K-tile, 16 MFMA each (p0: n-frags 0,1 / p1: n-frags 2,3).
// Ledger (steady, order-robust): p0 issues {bf01,bf23 (8 reg loads), stage A1[T+1]};
// p1 issues {stage A0[T+2]}. Compiler's waits for bf drains older FIFO entries;
// explicit VMCNT(2) at end of p1 guarantees A[T+1] landed (outstanding set is
// a subset of {A1[T+1], A0[T+2]}, A0 newest-2) before barrier -> collective.
template<int DO_SILU>
__global__ __launch_bounds__(512, 2)
void gemm_bt(const unsigned short* __restrict__ A, const unsigned short* __restrict__ Bt,
             void* __restrict__ Cptr, int M, int N, int K) {
    __shared__ __align__(16) unsigned short lds[2 * 16384];   // 64 KB: 2 bufs x 256x64

    const int t = threadIdx.x, lane = t & 63, w = t >> 6;
    const int wm = w >> 1, wn = w & 1;
    const int lr = lane & 15, lk = lane >> 4;

    // XCD swizzle, mb-major: xcd owns an mb-range, nb cycles fastest so
    // consecutive blocks share the A-panel (L2-hit) while B panels cycle.
    const int NB = N >> 7;                       // blocks along n
    const int f = blockIdx.x;
    const int xcd = f & 7, c = f >> 3;
    const int mb = xcd * ((gridDim.x >> 3) / NB) + c / NB;
    const int nb = c % NB;
    const int m0 = mb * 256, n0 = nb * 128;

    // LDS read-side swizzle (granule ^= row&7) and pre-swizzled staging source
    const int cswz0 = ((lk ^ (lr & 7)) * 8);
    const int cswz1 = (((4 + lk) ^ (lr & 7)) * 8);
    const int srow = lane >> 3;
    const int scol = ((lane & 7) ^ srow) * 8;

    auto stage_A = [&](int kt, int half) {
        const unsigned short* src = A + (size_t)(m0 + half * 128) * K + kt * 64;
        unsigned short* dst = &lds[(kt & 1) * 16384 + half * 8192];
        #pragma unroll
        for (int i = 0; i < 2; ++i) {
            int c2 = i * 8 + w;
            gload_lds16(src + (size_t)(c2 * 8 + srow) * K + scol, dst + c2 * 512);
        }
    };
    auto read_A = [&](int kt, bf16x8 (&af)[4][2]) {
        const unsigned short* base = &lds[(kt & 1) * 16384];
        #pragma unroll
        for (int m = 0; m < 4; ++m) {
            int rw = wm * 64 + m * 16 + lr;
            af[m][0] = *(const bf16x8*)(base + rw * 64 + cswz0);
            af[m][1] = *(const bf16x8*)(base + rw * 64 + cswz1);
        }
    };
    auto load_B = [&](int kt, bf16x8 (&bfr)[4][2]) {
        #pragma unroll
        for (int n = 0; n < 4; ++n) {
            const unsigned short* p = Bt + (size_t)(n0 + wn * 64 + n * 16 + lr) * K + kt * 64 + lk * 8;
            bfr[n][0] = *(const bf16x8*)(p);
            bfr[n][1] = *(const bf16x8*)(p + 32);
        }
    };

    f32x4 acc[4][4] = {};
    const int NT = K / 64;

    // prologue: A[0] both halves + A0[1]; vmcnt(2) -> A[0] landed, A0[1] in flight
    stage_A(0, 0); stage_A(0, 1); stage_A(1, 0);
    VMCNT(2);
    __builtin_amdgcn_s_barrier();
    __builtin_amdgcn_sched_barrier(0);

    for (int kt = 0; kt < NT; ++kt) {
        bf16x8 af[4][2], bfr[4][2];
        {   // p0: n-frags 0,1
            load_B(kt, bfr);                      // 8 reg loads (both halves, early)
            read_A(kt, af);                       // 8 ds_read_b128
            if (kt + 1 < NT) stage_A(kt + 1, 1);  // 2 gload_lds
            PHASE_MID();
            __builtin_amdgcn_s_setprio(1);
            #pragma unroll
            for (int m = 0; m < 4; ++m)
                #pragma unroll
                for (int n = 0; n < 2; ++n)
                    #pragma unroll
                    for (int ks = 0; ks < 2; ++ks)
                        acc[m][n] = __builtin_amdgcn_mfma_f32_16x16x32_bf16(
                            af[m][ks], bfr[n][ks], acc[m][n], 0, 0, 0);
            __builtin_amdgcn_s_setprio(0);
            PHASE_END();
        }
        {   // p1: n-frags 2,3 (same af)
            if (kt + 2 < NT) stage_A(kt + 2, 0);  // 2 gload_lds
            PHASE_MID();
            __builtin_amdgcn_s_setprio(1);
            #pragma unroll
            for (int m = 0; m < 4; ++m)
                #pragma unroll
                for (int n = 0; n < 2; ++n)
                    #pragma unroll
                    for (int ks = 0; ks < 2; ++ks)
                        acc[m][2 + n] = __builtin_amdgcn_mfma_f32_16x16x32_bf16(
                            af[m][ks], bfr[2 + n][ks], acc[m][2 + n], 0, 0, 0);
            __builtin_amdgcn_s_setprio(0);
            VMCNT(2);                              // A[kt+1] fully landed
            PHASE_END();
        }
    }

    // ---- epilogue ----
    #pragma unroll
    for (int m = 0; m < 4; ++m)
        #pragma unroll
        for (int n = 0; n < 4; ++n)
            #pragma unroll
            for (int r = 0; r < 4; ++r) {
                int row = m0 + wm * 64 + m * 16 + lk * 4 + r;
                int col = n0 + wn * 64 + n * 16 + lr;
                float v = acc[m][n][r];
                if (DO_SILU) {
                    v = v / (1.0f + __expf(-v));
                    ((unsigned short*)Cptr)[(size_t)row * N + col] = f2bf(v);
                } else {
                    ((float*)Cptr)[(size_t)row * N + col] = v;
                }
            }
}

extern "C" void kernel_launch(void* const* d_in, const int* in_sizes, int n_in,
                              void* d_out, int out_size, void* d_ws, size_t ws_size,
                              hipStream_t stream) {
    const float* x   = (const float*)d_in[0];
    const int*   idx = (const int*)d_in[1];
    const float* U   = (const float*)d_in[2];
    const float* V   = (const float*)d_in[3];
    float* out = (float*)d_out;

    unsigned short* Ut = (unsigned short*)d_ws;                 // [K_SUB][D_MODEL] bf16
    unsigned short* Vt = Ut + (size_t)K_SUB * D_MODEL;          // [D_MODEL][K_SUB] bf16
    unsigned short* P  = Vt + (size_t)K_SUB * D_MODEL;          // [N_TOK][K_SUB]  bf16
    unsigned short* xb = (unsigned short*)d_out;                // [N_TOK][D_MODEL] bf16 (temp)

    convert_x_kernel<<<(N_TOK * D_MODEL) / (256 * 8), 256, 0, stream>>>(x, xb);
    gather_u_t<<<(K_SUB / 64) * (D_MODEL / 64), 256, 0, stream>>>(U, idx, Ut);
    gather_v_t<<<(K_SUB / 64) * (D_MODEL / 64), 256, 0, stream>>>(V, idx, Vt);

    // GEMM1: P = silu(xb @ Usub)  M=8192 N=1024 K=4096; grid 32x8 = 256
    gemm_bt<1><<<256, 512, 0, stream>>>(xb, Ut, P, N_TOK, K_SUB, D_MODEL);
    // GEMM2: out = P @ Vsub       M=8192 N=4096 K=1024; grid 32x32 = 1024
    gemm_bt<0><<<1024, 512, 0, stream>>>(P, Vt, out, N_TOK, D_MODEL, K_SUB);
}

// Round 6
// 241.767 us; speedup vs baseline: 1.9735x; 1.9735x over previous
//
#include <hip/hip_runtime.h>
#include <hip/hip_bf16.h>
#include <stdint.h>

#define D_MODEL 4096
#define D_BASE  8192
#define K_SUB   1024
#define N_TOK   8192

typedef __attribute__((ext_vector_type(8))) short bf16x8;
typedef __attribute__((ext_vector_type(4))) float f32x4;

__device__ __forceinline__ unsigned short f2bf(float f) {
    union { float f; uint32_t u; } c; c.f = f;
    uint32_t u = c.u;
    uint32_t r = u + 0x7FFFu + ((u >> 16) & 1u);   // round-to-nearest-even
    return (unsigned short)(r >> 16);
}

__device__ __forceinline__ void gload_lds16(const void* g, void* l) {
    __builtin_amdgcn_global_load_lds(
        (__attribute__((address_space(1))) void*)g,
        (__attribute__((address_space(3))) void*)l, 16, 0, 0);
}

#define VMCNT(N) do { __builtin_amdgcn_sched_barrier(0); \
    asm volatile("s_waitcnt vmcnt(" #N ")" ::: "memory"); } while (0)
#define PHASE_MID() do { __builtin_amdgcn_sched_barrier(0); __builtin_amdgcn_s_barrier(); \
    asm volatile("s_waitcnt lgkmcnt(0)" ::: "memory"); __builtin_amdgcn_sched_barrier(0); } while (0)
#define PHASE_END() do { __builtin_amdgcn_sched_barrier(0); __builtin_amdgcn_s_barrier(); } while (0)

// x (f32) -> xb (bf16), 8 elems/thread
__global__ void convert_x_kernel(const float* __restrict__ x, unsigned short* __restrict__ xb) {
    int t = blockIdx.x * 256 + threadIdx.x;
    const float4* p = (const float4*)x + (size_t)t * 2;
    float4 a = p[0], b = p[1];
    ushort4 lo, hi;
    lo.x = f2bf(a.x); lo.y = f2bf(a.y); lo.z = f2bf(a.z); lo.w = f2bf(a.w);
    hi.x = f2bf(b.x); hi.y = f2bf(b.y); hi.z = f2bf(b.z); hi.w = f2bf(b.w);
    *(ushort4*)(xb + (size_t)t * 8) = lo;
    *(ushort4*)(xb + (size_t)t * 8 + 4) = hi;
}

// Ut[n][k] = bf16(U[k][idx[n]]). Block = 32 k-rows x ALL 1024 n.
// Read phase: each k-row swept by all 1024 lanes back-to-back -> L2 line-dedup
// within the row (~28KB fetched of 32KB region vs 16x overfetch before).
// Write phase: full 64B line per n-row -> perfectly coalesced, no write amp.
__global__ __launch_bounds__(256) void gather_u_s(const float* __restrict__ U,
                                                  const int* __restrict__ idx,
                                                  unsigned short* __restrict__ Ut) {
    __shared__ unsigned short tile[1024 * 36];   // stride 36: bank-spread, 8B-aligned
    __shared__ int lidx[1024];
    const int t = threadIdx.x;
    const int k0 = blockIdx.x * 32;
    #pragma unroll
    for (int i = 0; i < 4; ++i) lidx[i * 256 + t] = idx[i * 256 + t];
    __syncthreads();
    for (int kr = 0; kr < 32; ++kr) {
        const float* Urow = U + (size_t)(k0 + kr) * D_BASE;
        #pragma unroll
        for (int it = 0; it < 4; ++it) {
            int n = it * 256 + t;
            tile[n * 36 + kr] = f2bf(Urow[lidx[n]]);
        }
    }
    __syncthreads();
    #pragma unroll
    for (int r = 0; r < 4; ++r) {
        int n = r * 256 + t;
        unsigned short* drow = Ut + (size_t)n * D_MODEL + k0;
        #pragma unroll
        for (int j = 0; j < 8; ++j) {
            ushort4 v = *(const ushort4*)&tile[n * 36 + j * 4];
            *(ushort4*)(drow + j * 4) = v;
        }
    }
}

// Vt[d][n] = bf16(V[idx[n]][d]), via 64x64 LDS transpose tile.
__global__ __launch_bounds__(256) void gather_v_t(const float* __restrict__ V,
                                                  const int* __restrict__ idx,
                                                  unsigned short* __restrict__ Vt) {
    __shared__ unsigned short tile[64][66];
    __shared__ int lidx[64];
    const int t = threadIdx.x;
    const int n0 = (blockIdx.x & 15) * 64;
    const int d0 = (blockIdx.x >> 4) * 64;
    if (t < 64) lidx[t] = idx[n0 + t];
    __syncthreads();
    const int c = t & 63, r4 = t >> 6;
    #pragma unroll
    for (int p = 0; p < 16; ++p) {
        int nr = p * 4 + r4;
        tile[nr][c] = f2bf(V[(size_t)lidx[nr] * D_MODEL + d0 + c]);
    }
    __syncthreads();
    #pragma unroll
    for (int p = 0; p < 16; ++p) {
        int dr = p * 4 + r4;
        Vt[(size_t)(d0 + dr) * K_SUB + n0 + c] = tile[c][dr];
    }
}

// ---------------- GEMM1: P = silu(xb @ Usub), M=8192 N=1024 K=4096 ----------------
// BM=256 BN=128 BK=64. 8 waves 4M x 2N -> wave tile 64x64 (16 ds_read_b128/K-tile
// vs R4's 20). 4 phases per 2 K-tiles, 16 MFMA/phase. Slots A0,A1,B per parity.
// Stage plan per pair T: p0:{A1[T+1],B[T+1]} p1:{A0[T+2]} p2:{A1[T+2],B[T+2]}
// p3:{A0[T+3]}. Every overwrite >=1 barrier after the slot's last ds_read.
// FIFO invariant at pair entry: outstanding = {A0[T+1]} (2 loads).
// Waits: end-p1 vmcnt(2) (drains A[T+1],B[T+1]); end-p3 vmcnt(2) (drains
// A[T+2],B[T+2]). Tail pair: end-p1 vmcnt(0), no later stages/waits.
__global__ __launch_bounds__(512, 2)
void gemm1_8p(const unsigned short* __restrict__ A, const unsigned short* __restrict__ Bt,
              unsigned short* __restrict__ C) {
    constexpr int K = D_MODEL, N = K_SUB, NT = K / 64;   // NT=64 (even)
    __shared__ __align__(16) unsigned short lds[49152];  // 96 KB: 2 x (A:16K + B:8K ushorts)

    const int t = threadIdx.x, lane = t & 63, w = t >> 6;
    const int wm = w >> 1, wn = w & 1;                   // 4M x 2N
    const int lr = lane & 15, lk = lane >> 4;

    // T1 XCD swizzle: 256 blocks -> each XCD: 4 mb x all 8 nb
    const int f = blockIdx.x;
    const int g = (f & 7) * 32 + (f >> 3);
    const int m0 = (g >> 3) * 256, n0 = (g & 7) * 128;

    const int cswz0 = ((lk ^ (lr & 7)) * 8);
    const int cswz1 = (((4 + lk) ^ (lr & 7)) * 8);
    const int srow = lane >> 3;
    const int scol = ((lane & 7) ^ srow) * 8;

    auto stage_A = [&](int kt, int half) {
        const unsigned short* src = A + (size_t)(m0 + half * 128) * K + kt * 64;
        unsigned short* dst = &lds[(kt & 1) * 24576 + half * 8192];
        #pragma unroll
        for (int i = 0; i < 2; ++i) {
            int c2 = i * 8 + w;
            gload_lds16(src + (size_t)(c2 * 8 + srow) * K + scol, dst + c2 * 512);
        }
    };
    auto stage_B = [&](int kt) {
        const unsigned short* src = Bt + (size_t)n0 * K + kt * 64;
        unsigned short* dst = &lds[(kt & 1) * 24576 + 16384];
        #pragma unroll
        for (int i = 0; i < 2; ++i) {
            int c2 = i * 8 + w;
            gload_lds16(src + (size_t)(c2 * 8 + srow) * K + scol, dst + c2 * 512);
        }
    };
    auto read_A = [&](int kt, bf16x8 (&af)[4][2]) {
        const unsigned short* base = &lds[(kt & 1) * 24576 + (wm >> 1) * 8192];
        #pragma unroll
        for (int m = 0; m < 4; ++m) {
            int rw = (wm & 1) * 64 + m * 16 + lr;
            af[m][0] = *(const bf16x8*)(base + rw * 64 + cswz0);
            af[m][1] = *(const bf16x8*)(base + rw * 64 + cswz1);
        }
    };
    auto read_B2 = [&](int kt, int nh, bf16x8 (&bfr)[2][2]) {   // n-frags {nh*2, nh*2+1}
        const unsigned short* base = &lds[(kt & 1) * 24576 + 16384];
        #pragma unroll
        for (int n = 0; n < 2; ++n) {
            int rw = wn * 64 + (nh * 2 + n) * 16 + lr;
            bfr[n][0] = *(const bf16x8*)(base + rw * 64 + cswz0);
            bfr[n][1] = *(const bf16x8*)(base + rw * 64 + cswz1);
        }
    };

    f32x4 acc[4][4] = {};

    // prologue: A0[0],A1[0],B[0] drained; A0[1] in flight -> invariant {A0[1]}
    stage_A(0, 0); stage_A(0, 1); stage_B(0); stage_A(1, 0);
    VMCNT(2);
    __builtin_amdgcn_s_barrier();
    __builtin_amdgcn_sched_barrier(0);

    for (int kt = 0; kt < NT; kt += 2) {
        const bool more = (kt + 2 < NT);
        {   // p0: tile kt, n-frags 0,1
            bf16x8 af[4][2], bfr[2][2];
            read_A(kt, af); read_B2(kt, 0, bfr);
            stage_A(kt + 1, 1); stage_B(kt + 1);
            PHASE_MID();
            __builtin_amdgcn_s_setprio(1);
            #pragma unroll
            for (int m = 0; m < 4; ++m)
                #pragma unroll
                for (int n = 0; n < 2; ++n)
                    #pragma unroll
                    for (int ks = 0; ks < 2; ++ks)
                        acc[m][n] = __builtin_amdgcn_mfma_f32_16x16x32_bf16(
                            af[m][ks], bfr[n][ks], acc[m][n], 0, 0, 0);
            __builtin_amdgcn_s_setprio(0);
            PHASE_END();
            // p1: tile kt, n-frags 2,3 (af reused)
            bf16x8 bfr2[2][2];
            read_B2(kt, 1, bfr2);
            if (more) stage_A(kt + 2, 0);
            PHASE_MID();
            __builtin_amdgcn_s_setprio(1);
            #pragma unroll
            for (int m = 0; m < 4; ++m)
                #pragma unroll
                for (int n = 0; n < 2; ++n)
                    #pragma unroll
                    for (int ks = 0; ks < 2; ++ks)
                        acc[m][2 + n] = __builtin_amdgcn_mfma_f32_16x16x32_bf16(
                            af[m][ks], bfr2[n][ks], acc[m][2 + n], 0, 0, 0);
            __builtin_amdgcn_s_setprio(0);
            if (more) { VMCNT(2); } else { VMCNT(0); }
            PHASE_END();
        }
        {   // p2: tile kt+1, n-frags 0,1
            bf16x8 af[4][2], bfr[2][2];
            read_A(kt + 1, af); read_B2(kt + 1, 0, bfr);
            if (more) { stage_A(kt + 2, 1); stage_B(kt + 2); }
            PHASE_MID();
            __builtin_amdgcn_s_setprio(1);
            #pragma unroll
            for (int m = 0; m < 4; ++m)
                #pragma unroll
                for (int n = 0; n < 2; ++n)
                    #pragma unroll
                    for (int ks = 0; ks < 2; ++ks)
                        acc[m][n] = __builtin_amdgcn_mfma_f32_16x16x32_bf16(
                            af[m][ks], bfr[n][ks], acc[m][n], 0, 0, 0);
            __builtin_amdgcn_s_setprio(0);
            PHASE_END();
            // p3: tile kt+1, n-frags 2,3
            bf16x8 bfr2[2][2];
            read_B2(kt + 1, 1, bfr2);
            if (more) stage_A(kt + 3, 0);
            PHASE_MID();
            __builtin_amdgcn_s_setprio(1);
            #pragma unroll
            for (int m = 0; m < 4; ++m)
                #pragma unroll
                for (int n = 0; n < 2; ++n)
                    #pragma unroll
                    for (int ks = 0; ks < 2; ++ks)
                        acc[m][2 + n] = __builtin_amdgcn_mfma_f32_16x16x32_bf16(
                            af[m][ks], bfr2[n][ks], acc[m][2 + n], 0, 0, 0);
            __builtin_amdgcn_s_setprio(0);
            if (more) VMCNT(2);
            PHASE_END();
        }
    }

    #pragma unroll
    for (int m = 0; m < 4; ++m)
        #pragma unroll
        for (int n = 0; n < 4; ++n)
            #pragma unroll
            for (int r = 0; r < 4; ++r) {
                int row = m0 + wm * 64 + m * 16 + lk * 4 + r;
                int col = n0 + wn * 64 + n * 16 + lr;
                float v = acc[m][n][r];
                v = v / (1.0f + __expf(-v));
                C[(size_t)row * N + col] = f2bf(v);
            }
}

// ---------------- GEMM2: out = P @ Vsub, M=8192 N=4096 K=1024 ----------------
// R4-proven 4-quadrant schedule (16 MFMA/phase), 256x256, + T1 swizzle. Unchanged.
__global__ __launch_bounds__(512, 2)
void gemm2_8p(const unsigned short* __restrict__ A, const unsigned short* __restrict__ Bt,
              float* __restrict__ C) {
    constexpr int K = K_SUB, N = D_MODEL, NT = K / 64;   // NT=16
    constexpr int BUFSZ = 32768;                          // (256+256)*64 ushorts
    __shared__ __align__(16) unsigned short lds[2 * BUFSZ];   // 128 KB

    const int t = threadIdx.x, lane = t & 63, w = t >> 6;
    const int wr = w >> 2, wc = w & 3;
    const int lr = lane & 15, lk = lane >> 4;

    const int f = blockIdx.x;
    const int g = (f & 7) * 64 + (f >> 3);
    const int m0 = (g >> 4) * 256, n0 = (g & 15) * 256;

    const int cswz0 = ((lk ^ (lr & 7)) * 8);
    const int cswz1 = (((4 + lk) ^ (lr & 7)) * 8);
    const int srow = lane >> 3;
    const int scol = ((lane & 7) ^ srow) * 8;

    auto stage_A = [&](int kt, int mh) {
        const unsigned short* src = A + (size_t)(m0 + mh * 128) * K + kt * 64;
        unsigned short* dst = &lds[(kt & 1) * BUFSZ + mh * 8192];
        #pragma unroll
        for (int i = 0; i < 2; ++i) {
            int c2 = i * 8 + w;
            gload_lds16(src + (size_t)(c2 * 8 + srow) * K + scol, dst + c2 * 512);
        }
    };
    auto stage_B = [&](int kt, int nh) {
        const unsigned short* src = Bt + (size_t)(n0 + nh * 128) * K + kt * 64;
        unsigned short* dst = &lds[(kt & 1) * BUFSZ + 16384 + nh * 8192];
        #pragma unroll
        for (int i = 0; i < 2; ++i) {
            int c2 = i * 8 + w;
            gload_lds16(src + (size_t)(c2 * 8 + srow) * K + scol, dst + c2 * 512);
        }
    };
    auto read_A = [&](int kt, int mh, bf16x8 (&af)[4][2]) {
        const unsigned short* base = &lds[(kt & 1) * BUFSZ + mh * 8192];
        #pragma unroll
        for (int m = 0; m < 4; ++m) {
            int rw = wr * 64 + m * 16 + lr;
            af[m][0] = *(const bf16x8*)(base + rw * 64 + cswz0);
            af[m][1] = *(const bf16x8*)(base + rw * 64 + cswz1);
        }
    };
    auto read_B = [&](int kt, int nh, bf16x8 (&bfr)[2][2]) {
        const unsigned short* base = &lds[(kt & 1) * BUFSZ + 16384 + nh * 8192];
        #pragma unroll
        for (int n = 0; n < 2; ++n) {
            int rw = wc * 32 + n * 16 + lr;
            bfr[n][0] = *(const bf16x8*)(base + rw * 64 + cswz0);
            bfr[n][1] = *(const bf16x8*)(base + rw * 64 + cswz1);
        }
    };

    f32x4 acc[8][4] = {};

    stage_A(0, 0); stage_B(0, 0); stage_B(0, 1); stage_A(0, 1);
    stage_A(1, 0); stage_B(1, 1); stage_A(1, 1);
    VMCNT(6);
    __builtin_amdgcn_s_barrier();
    __builtin_amdgcn_sched_barrier(0);

    for (int kt = 0; kt < NT; ++kt) {
        bf16x8 af[4][2], bf0[2][2], bf1[2][2];
        {   // p0: quadrant (0,0)
            read_A(kt, 0, af); read_B(kt, 0, bf0);
            if (kt + 1 < NT) stage_B(kt + 1, 0);
            PHASE_MID();
            __builtin_amdgcn_s_setprio(1);
            #pragma unroll
            for (int m = 0; m < 4; ++m)
                #pragma unroll
                for (int n = 0; n < 2; ++n)
                    #pragma unroll
                    for (int ks = 0; ks < 2; ++ks)
                        acc[m][n] = __builtin_amdgcn_mfma_f32_16x16x32_bf16(
                            af[m][ks], bf0[n][ks], acc[m][n], 0, 0, 0);
            __builtin_amdgcn_s_setprio(0);
            PHASE_END();
        }
        {   // p1: quadrant (0,1)
            read_B(kt, 1, bf1);
            if (kt + 2 < NT) stage_A(kt + 2, 0);
            PHASE_MID();
            __builtin_amdgcn_s_setprio(1);
            #pragma unroll
            for (int m = 0; m < 4; ++m)
                #pragma unroll
                for (int n = 0; n < 2; ++n)
                    #pragma unroll
                    for (int ks = 0; ks < 2; ++ks)
                        acc[m][2 + n] = __builtin_amdgcn_mfma_f32_16x16x32_bf16(
                            af[m][ks], bf1[n][ks], acc[m][2 + n], 0, 0, 0);
            __builtin_amdgcn_s_setprio(0);
            PHASE_END();
        }
        {   // p2: quadrant (1,0)
            read_A(kt, 1, af);
            if (kt + 2 < NT) stage_B(kt + 2, 1);
            PHASE_MID();
            __builtin_amdgcn_s_setprio(1);
            #pragma unroll
            for (int m = 0; m < 4; ++m)
                #pragma unroll
                for (int n = 0; n < 2; ++n)
                    #pragma unroll
                    for (int ks = 0; ks < 2; ++ks)
                        acc[4 + m][n] = __builtin_amdgcn_mfma_f32_16x16x32_bf16(
                            af[m][ks], bf0[n][ks], acc[4 + m][n], 0, 0, 0);
            __builtin_amdgcn_s_setprio(0);
            PHASE_END();
        }
        {   // p3: quadrant (1,1)
            if (kt + 2 < NT) stage_A(kt + 2, 1);
            PHASE_MID();
            __builtin_amdgcn_s_setprio(1);
            #pragma unroll
            for (int m = 0; m < 4; ++m)
                #pragma unroll
                for (int n = 0; n < 2; ++n)
                    #pragma unroll
                    for (int ks = 0; ks < 2; ++ks)
                        acc[4 + m][2 + n] = __builtin_amdgcn_mfma_f32_16x16x32_bf16(
                            af[m][ks], bf1[n][ks], acc[4 + m][2 + n], 0, 0, 0);
            __builtin_amdgcn_s_setprio(0);
            __builtin_amdgcn_sched_barrier(0);
            if (kt < NT - 2) { VMCNT(6); }
            else if (kt == NT - 2) { VMCNT(0); }
            PHASE_END();
        }
    }

    #pragma unroll
    for (int mh = 0; mh < 2; ++mh)
        #pragma unroll
        for (int nh = 0; nh < 2; ++nh)
            #pragma unroll
            for (int m = 0; m < 4; ++m)
                #pragma unroll
                for (int n = 0; n < 2; ++n)
                    #pragma unroll
                    for (int r = 0; r < 4; ++r) {
                        int row = m0 + mh * 128 + wr * 64 + m * 16 + lk * 4 + r;
                        int col = n0 + nh * 128 + wc * 32 + n * 16 + lr;
                        C[(size_t)row * N + col] = acc[mh * 4 + m][nh * 2 + n][r];
                    }
}

extern "C" void kernel_launch(void* const* d_in, const int* in_sizes, int n_in,
                              void* d_out, int out_size, void* d_ws, size_t ws_size,
                              hipStream_t stream) {
    const float* x   = (const float*)d_in[0];
    const int*   idx = (const int*)d_in[1];
    const float* U   = (const float*)d_in[2];
    const float* V   = (const float*)d_in[3];
    float* out = (float*)d_out;

    unsigned short* Ut = (unsigned short*)d_ws;                 // [K_SUB][D_MODEL] bf16
    unsigned short* Vt = Ut + (size_t)K_SUB * D_MODEL;          // [D_MODEL][K_SUB] bf16
    unsigned short* P  = Vt + (size_t)K_SUB * D_MODEL;          // [N_TOK][K_SUB]  bf16
    unsigned short* xb = (unsigned short*)d_out;                // [N_TOK][D_MODEL] bf16 (temp)

    convert_x_kernel<<<(N_TOK * D_MODEL) / (256 * 8), 256, 0, stream>>>(x, xb);
    gather_u_s<<<D_MODEL / 32, 256, 0, stream>>>(U, idx, Ut);
    gather_v_t<<<(K_SUB / 64) * (D_MODEL / 64), 256, 0, stream>>>(V, idx, Vt);

    gemm1_8p<<<256, 512, 0, stream>>>(xb, Ut, P);
    gemm2_8p<<<512, 512, 0, stream>>>(P, Vt, out);
}